// Round 1
// baseline (90.471 us; speedup 1.0000x reference)
//
#include <hip/hip_runtime.h>

// StaticKVCache steady-state step: ring write + roll + concat, expressed as a
// pure gather into the output. Every output element is a copy of exactly one
// input element, so the kernel is a single coalesced permutation-copy.
//
// Shapes (B=1): sink [3072,16,128], local [12288,16,128], new [1024,16,128].
// Output: [2, 15360, 16, 128] f32  (kv-stacked full_k, full_v).
//
// Row mapping for output row t (0..15359):
//   t < SINK          -> sink row t
//   else tt = t-SINK  -> ring row r0 = (tt + new_write_idx) % LOCAL
//       d = (r0 - write_idx) mod LOCAL
//       d < NEW_LEN   -> new row d          (freshly written slot)
//       else          -> local row r0       (untouched ring slot)

constexpr int SINK    = 3 * 1024;    // 3072
constexpr int LOCAL   = 12 * 1024;   // 12288
constexpr int NEW_LEN = 1024;
constexpr int T_FULL  = SINK + LOCAL;  // 15360
constexpr int HD      = 16 * 128;      // 2048 floats per row
constexpr int ROWV4   = HD / 4;        // 512 float4 per row

__global__ __launch_bounds__(ROWV4) void kv_linearize_kernel(
    const float4* __restrict__ sink_k, const float4* __restrict__ sink_v,
    const float4* __restrict__ local_k, const float4* __restrict__ local_v,
    const float4* __restrict__ new_k, const float4* __restrict__ new_v,
    const int* __restrict__ write_idx_p,
    float4* __restrict__ out)
{
    const int t  = blockIdx.x;   // 0..T_FULL-1 (linearized seq position)
    const int kv = blockIdx.y;   // 0 = K, 1 = V
    const int c  = threadIdx.x;  // 0..ROWV4-1 (float4 column within row)

    const float4* __restrict__ sink = kv ? sink_v : sink_k;
    const float4* __restrict__ loc  = kv ? local_v : local_k;
    const float4* __restrict__ nw   = kv ? new_v  : new_k;

    float4 val;
    if (t < SINK) {
        val = sink[(size_t)t * ROWV4 + c];
    } else {
        // write_idx is a runtime scalar; normalize into [0, LOCAL)
        int wi = write_idx_p[0] % LOCAL;
        if (wi < 0) wi += LOCAL;
        int nwi = wi + NEW_LEN;            // new_write_idx
        if (nwi >= LOCAL) nwi -= LOCAL;

        int r0 = (t - SINK) + nwi;         // roll by -new_write_idx
        if (r0 >= LOCAL) r0 -= LOCAL;

        int d = r0 - wi;                   // distance into the written window
        if (d < 0) d += LOCAL;

        val = (d < NEW_LEN) ? nw[(size_t)d * ROWV4 + c]
                            : loc[(size_t)r0 * ROWV4 + c];
    }
    out[((size_t)kv * T_FULL + t) * ROWV4 + c] = val;
}

extern "C" void kernel_launch(void* const* d_in, const int* in_sizes, int n_in,
                              void* d_out, int out_size, void* d_ws, size_t ws_size,
                              hipStream_t stream) {
    const float4* sink_k  = (const float4*)d_in[0];
    const float4* sink_v  = (const float4*)d_in[1];
    const float4* local_k = (const float4*)d_in[2];
    const float4* local_v = (const float4*)d_in[3];
    const float4* new_k   = (const float4*)d_in[4];
    const float4* new_v   = (const float4*)d_in[5];
    const int*    widx    = (const int*)d_in[6];
    float4*       out     = (float4*)d_out;

    dim3 grid(T_FULL, 2);
    dim3 block(ROWV4);
    kv_linearize_kernel<<<grid, block, 0, stream>>>(
        sink_k, sink_v, local_k, local_v, new_k, new_v, widx, out);
}

// Round 3
// 84.682 us; speedup vs baseline: 1.0684x; 1.0684x over previous
//
#include <hip/hip_runtime.h>

// StaticKVCache steady-state step: ring write + roll + concat as a pure
// permutation-copy gather. One block per output row t; the block handles BOTH
// K and V (identical row mapping) -> 2 independent load/store chains per
// thread for memory-level parallelism. Nontemporal hints: every byte is
// touched exactly once, so cache retention is pure pollution.
//
// Row mapping for output row t (0..15359):
//   t < SINK          -> sink row t
//   else tt = t-SINK  -> ring row r0 = (tt + new_write_idx) % LOCAL
//       d = (r0 - write_idx) mod LOCAL
//       d < NEW_LEN   -> new row d          (freshly written slot)
//       else          -> local row r0       (untouched ring slot)

constexpr int SINK    = 3 * 1024;    // 3072
constexpr int LOCAL   = 12 * 1024;   // 12288
constexpr int NEW_LEN = 1024;
constexpr int T_FULL  = SINK + LOCAL;  // 15360
constexpr int HD      = 16 * 128;      // 2048 floats per row
constexpr int ROWV4   = HD / 4;        // 512 float4 per row

// Native clang vector type: __builtin_nontemporal_* requires it
// (HIP_vector_type float4 is a struct and is rejected).
typedef float f4 __attribute__((ext_vector_type(4)));

__global__ __launch_bounds__(ROWV4) void kv_linearize_kernel(
    const f4* __restrict__ sink_k, const f4* __restrict__ sink_v,
    const f4* __restrict__ local_k, const f4* __restrict__ local_v,
    const f4* __restrict__ new_k, const f4* __restrict__ new_v,
    const int* __restrict__ write_idx_p,
    f4* __restrict__ out)
{
    const int t = blockIdx.x;   // 0..T_FULL-1 (linearized seq position)
    const int c = threadIdx.x;  // 0..ROWV4-1 (float4 column within row)

    const f4* __restrict__ srcK;
    const f4* __restrict__ srcV;

    if (t < SINK) {
        srcK = sink_k + (size_t)t * ROWV4;
        srcV = sink_v + (size_t)t * ROWV4;
    } else {
        // write_idx is a runtime scalar; normalize into [0, LOCAL)
        int wi = write_idx_p[0] % LOCAL;
        if (wi < 0) wi += LOCAL;
        int nwi = wi + NEW_LEN;            // new_write_idx
        if (nwi >= LOCAL) nwi -= LOCAL;

        int r0 = (t - SINK) + nwi;         // roll by -new_write_idx
        if (r0 >= LOCAL) r0 -= LOCAL;

        int d = r0 - wi;                   // distance into the written window
        if (d < 0) d += LOCAL;

        if (d < NEW_LEN) {
            srcK = new_k + (size_t)d * ROWV4;
            srcV = new_v + (size_t)d * ROWV4;
        } else {
            srcK = local_k + (size_t)r0 * ROWV4;
            srcV = local_v + (size_t)r0 * ROWV4;
        }
    }

    // Two independent load->store chains (K and V) per thread: 2x MLP.
    f4 vk = __builtin_nontemporal_load(srcK + c);
    f4 vv = __builtin_nontemporal_load(srcV + c);
    __builtin_nontemporal_store(vk, out + (size_t)t * ROWV4 + c);
    __builtin_nontemporal_store(vv, out + ((size_t)T_FULL + t) * ROWV4 + c);
}

extern "C" void kernel_launch(void* const* d_in, const int* in_sizes, int n_in,
                              void* d_out, int out_size, void* d_ws, size_t ws_size,
                              hipStream_t stream) {
    const f4* sink_k  = (const f4*)d_in[0];
    const f4* sink_v  = (const f4*)d_in[1];
    const f4* local_k = (const f4*)d_in[2];
    const f4* local_v = (const f4*)d_in[3];
    const f4* new_k   = (const f4*)d_in[4];
    const f4* new_v   = (const f4*)d_in[5];
    const int*  widx  = (const int*)d_in[6];
    f4*         out   = (f4*)d_out;

    dim3 grid(T_FULL);
    dim3 block(ROWV4);
    kv_linearize_kernel<<<grid, block, 0, stream>>>(
        sink_k, sink_v, local_k, local_v, new_k, new_v, widx, out);
}